// Round 10
// baseline (177.651 us; speedup 1.0000x reference)
//
#include <hip/hip_runtime.h>
#include <math.h>

#define B_N 131072

// ---------------- ws layout (float offsets) ----------------
#define WS_STAT1 0
#define ST1_SZ   (64 * 352)          // 22528
#define WS_MT    22528               // Mt[64][20]
#define WS_C     23808               // C[20]
#define WS_STAT2 23840               // 64 stripes x 40 -> 26400
#define WS_NH    26400               // nhu[200], nhl[200] -> 26800
#define WS_RBFF  26816               // [0]=flag, [8..40)=per-g {c0,k1,nh0,lin}, [64..128)=W
#define WS_RBFX  26944               // exact: c[64], w[64], nh[64]
#define WS_Z     28672               // z col-major [20][B]
#define WS_END   (WS_Z + (size_t)B_N * 20)

__device__ __forceinline__ float gelu_exact(float v) {
    return 0.5f * v * (1.0f + erff(v * 0.70710678118654752440f));
}

// ---------------- pass 1: RBF -> act moments only (no act store) ----------------
__global__ __launch_bounds__(256) void k_act_moments(
    const float* __restrict__ x, const float* __restrict__ cen,
    const float* __restrict__ lw, const float* __restrict__ rw,
    const float* __restrict__ linw, float* __restrict__ stat1)
{
    __shared__ float sAcc[4][8][44];
    const int t = threadIdx.x;
    const int g = t & 7;
    const int rl = t >> 3;

    float c_[8], nh_[8], w_[8];
#pragma unroll
    for (int k = 0; k < 8; ++k) {
        c_[k] = cen[g * 8 + k];
        float s = expf(lw[g * 8 + k]) + 1e-6f;
        nh_[k] = -0.5f / (s * s);
        w_[k] = rw[g * 8 + k];
    }
    const float lin = linw[g];
    const float c0 = c_[0], nh0 = nh_[0];
    const float delta = c_[1] - c_[0];

    bool uni = true;
#pragma unroll
    for (int k = 0; k < 8; ++k) {
        float ck = c0 + (float)k * delta;
        uni = uni && (fabsf(c_[k] - ck) <= 1e-5f * (1.0f + fabsf(ck)));
        uni = uni && (fabsf(nh_[k] - nh0) <= 1e-6f * fabsf(nh0));
    }
    const bool fast = (bool)__all((int)uni);

    float W_[8];
    float k1 = 0.0f;
    if (fast) {
        k1 = -2.0f * delta * nh0;
#pragma unroll
        for (int k = 0; k < 8; ++k) {
            float kd = (float)k * delta;
            W_[k] = w_[k] * __expf(nh0 * kd * kd);
        }
    }

    float sumA[8], P[36];
#pragma unroll
    for (int f = 0; f < 8; ++f) sumA[f] = 0.0f;
#pragma unroll
    for (int i = 0; i < 36; ++i) P[i] = 0.0f;

    if (fast) {
#pragma unroll 1
        for (int row = blockIdx.x * 32 + rl; row < B_N; row += gridDim.x * 32) {
            const float* xr = x + (size_t)row * 64 + g * 8;
            float4 v0 = *(const float4*)(xr);
            float4 v1 = *(const float4*)(xr + 4);
            float xv[8] = {v0.x, v0.y, v0.z, v0.w, v1.x, v1.y, v1.z, v1.w};
            float act[8];
#pragma unroll
            for (int f = 0; f < 8; ++f) {
                float v = xv[f];
                float dv = v - c0;
                float E0 = __expf(nh0 * dv * dv);
                float T  = __expf(k1 * dv);
                float poly = W_[7];
#pragma unroll
                for (int k = 6; k >= 0; --k) poly = poly * T + W_[k];
                act[f] = lin * v + E0 * poly;
            }
            int idx = 0;
#pragma unroll
            for (int f = 0; f < 8; ++f) {
                sumA[f] += act[f];
#pragma unroll
                for (int f2 = 0; f2 <= f; ++f2) { P[idx] += act[f] * act[f2]; ++idx; }
            }
        }
    } else {
#pragma unroll 1
        for (int row = blockIdx.x * 32 + rl; row < B_N; row += gridDim.x * 32) {
            const float* xr = x + (size_t)row * 64 + g * 8;
            float4 v0 = *(const float4*)(xr);
            float4 v1 = *(const float4*)(xr + 4);
            float xv[8] = {v0.x, v0.y, v0.z, v0.w, v1.x, v1.y, v1.z, v1.w};
            float act[8];
#pragma unroll
            for (int f = 0; f < 8; ++f) {
                float v = xv[f];
                float a = lin * v;
#pragma unroll
                for (int k = 0; k < 8; ++k) {
                    float d = v - c_[k];
                    a += w_[k] * __expf(d * d * nh_[k]);
                }
                act[f] = a;
            }
            int idx = 0;
#pragma unroll
            for (int f = 0; f < 8; ++f) {
                sumA[f] += act[f];
#pragma unroll
                for (int f2 = 0; f2 <= f; ++f2) { P[idx] += act[f] * act[f2]; ++idx; }
            }
        }
    }

#pragma unroll
    for (int off = 32; off >= 8; off >>= 1) {
#pragma unroll
        for (int f = 0; f < 8; ++f) sumA[f] += __shfl_down(sumA[f], off, 64);
#pragma unroll
        for (int i = 0; i < 36; ++i) P[i] += __shfl_down(P[i], off, 64);
    }
    const int wave = t >> 6, lane = t & 63;
    if (lane < 8) {   // lane == g
        float* dst = &sAcc[wave][lane][0];
#pragma unroll
        for (int f = 0; f < 8; ++f) dst[f] = sumA[f];
#pragma unroll
        for (int i = 0; i < 36; ++i) dst[8 + i] = P[i];
    }
    __syncthreads();
    for (int i = t; i < 352; i += 256) {
        int gg = i / 44, v = i % 44;
        float s = sAcc[0][gg][v] + sAcc[1][gg][v] + sAcc[2][gg][v] + sAcc[3][gg][v];
        atomicAdd(&stat1[(blockIdx.x & 63) * 352 + i], s);
    }
}

// ---------------- build: BN1 fold -> Mt/C, fuzzy + RBF tables, zero stat2 ----------------
__global__ __launch_bounds__(256) void k_build(
    const float* __restrict__ stat1, const float* __restrict__ fpW,
    const float* __restrict__ fpb, const float* __restrict__ g1,
    const float* __restrict__ b1, const float* __restrict__ Wp,
    const float* __restrict__ pb, const float* __restrict__ lsu,
    const float* __restrict__ lsl, const float* __restrict__ cen,
    const float* __restrict__ lw, const float* __restrict__ rw,
    const float* __restrict__ linw,
    float* __restrict__ Mt, float* __restrict__ Cc, float* __restrict__ nh,
    float* __restrict__ stat2, float* __restrict__ rbff, float* __restrict__ rbfx)
{
    __shared__ float Am[8][8];
    __shared__ float Sg[8][36];
    __shared__ float a_[128], bb_[128];
    const int t = threadIdx.x;
    for (int i = t; i < 352; i += 256) {
        float s = 0.0f;
        for (int st = 0; st < 64; ++st) s += stat1[st * 352 + i];
        float m = s * (1.0f / B_N);
        int g = i / 44, v = i % 44;
        if (v < 8) Am[g][v] = m; else Sg[g][v - 8] = m;
    }
    __syncthreads();
    if (t < 128) {
        const int g = t >> 4;
        float wv[8];
#pragma unroll
        for (int f = 0; f < 8; ++f) wv[f] = Wp[t * 8 + f];
        float dot = 0.0f;
#pragma unroll
        for (int f = 0; f < 8; ++f) dot += wv[f] * Am[g][f];
        const float pbv = pb[t];
        const float mu = pbv + dot;
        float e2 = pbv * pbv + 2.0f * pbv * dot;
        int idx = 0;
#pragma unroll
        for (int f = 0; f < 8; ++f)
#pragma unroll
            for (int f2 = 0; f2 <= f; ++f2) {
                float c2 = (f2 == f) ? 1.0f : 2.0f;
                e2 += c2 * wv[f] * wv[f2] * Sg[g][idx]; ++idx;
            }
        const float var = fmaxf(e2 - mu * mu, 0.0f);
        const float a = g1[t] * rsqrtf(var + 1e-5f);
        a_[t] = a;
        bb_[t] = b1[t] - mu * a;
    }
    __syncthreads();
    for (int i = t; i < 1280; i += 256) {
        int gf = i / 20, j = i % 20;
        int g = gf >> 3, f = gf & 7;
        float m = 0.0f;
        for (int o = 0; o < 16; ++o) {
            int c = g * 16 + o;
            m += fpW[j * 128 + c] * a_[c] * Wp[c * 8 + f];
        }
        Mt[i] = m;
    }
    if (t < 20) {
        float cj = fpb[t];
        for (int c = 0; c < 128; ++c)
            cj += fpW[t * 128 + c] * (a_[c] * pb[c] + bb_[c]);
        Cc[t] = cj;
    }
    for (int i = t; i < 200; i += 256) {
        float su = expf(lsu[i]) + 1e-6f;
        float sl = fminf(expf(lsl[i]) + 1e-6f, 0.9f * su);
        nh[i] = -0.5f / (su * su);
        nh[200 + i] = -0.5f / (sl * sl);
    }
    for (int i = t; i < 2560; i += 256) stat2[i] = 0.0f;

    // ---- RBF tables for k_z ----
    if (t < 64) {   // exact tables
        float s = expf(lw[t]) + 1e-6f;
        rbfx[t]        = cen[t];
        rbfx[64 + t]   = rw[t];
        rbfx[128 + t]  = -0.5f / (s * s);
    }
    if (t < 8) {    // per-group fast params
        const int g = t;
        float c0 = cen[g * 8];
        float delta = cen[g * 8 + 1] - c0;
        float s0 = expf(lw[g * 8]) + 1e-6f;
        float nh0 = -0.5f / (s0 * s0);
        rbff[8 + g * 4 + 0] = c0;
        rbff[8 + g * 4 + 1] = -2.0f * delta * nh0;
        rbff[8 + g * 4 + 2] = nh0;
        rbff[8 + g * 4 + 3] = linw[g];
    }
    if (t >= 64 && t < 128) {   // W table (index t-64)
        const int i = t - 64;
        const int g = i >> 3, k = i & 7;
        float delta = cen[g * 8 + 1] - cen[g * 8];
        float s0 = expf(lw[g * 8]) + 1e-6f;
        float nh0 = -0.5f / (s0 * s0);
        float kd = (float)k * delta;
        rbff[64 + i] = rw[i] * __expf(nh0 * kd * kd);
    }
    if (t == 0) {   // uniformity flag
        bool uni = true;
        for (int g = 0; g < 8; ++g) {
            float c0 = cen[g * 8];
            float delta = cen[g * 8 + 1] - c0;
            float s0 = expf(lw[g * 8]) + 1e-6f;
            float nh0 = -0.5f / (s0 * s0);
            for (int k = 0; k < 8; ++k) {
                float ck = c0 + (float)k * delta;
                uni = uni && (fabsf(cen[g * 8 + k] - ck) <= 1e-5f * (1.0f + fabsf(ck)));
                float sk = expf(lw[g * 8 + k]) + 1e-6f;
                float nhk = -0.5f / (sk * sk);
                uni = uni && (fabsf(nhk - nh0) <= 1e-6f * fabsf(nh0));
            }
        }
        rbff[0] = uni ? 1.0f : 0.0f;
    }
}

// ---------------- pass 2: RBF recompute (scalar tables) -> z, BN2 stats ----------------
__global__ __launch_bounds__(256) void k_z(
    const float* __restrict__ x, const float* __restrict__ Mt,
    const float* __restrict__ Cc, const float* __restrict__ rbff,
    const float* __restrict__ rbfx, const float* __restrict__ linw,
    float* __restrict__ zout, float* __restrict__ stat2)
{
    __shared__ float sRed[4][40];
    const int t = threadIdx.x;
    const int row = blockIdx.x * 256 + t;
    const float* xr = x + (size_t)row * 64;

    float zp[20];
#pragma unroll
    for (int j = 0; j < 20; ++j) zp[j] = Cc[j];   // uniform -> s_load

    const bool fast = rbff[0] > 0.5f;             // wave-uniform branch
    if (fast) {
#pragma unroll 1
        for (int g = 0; g < 8; ++g) {
            const float c0  = rbff[8 + g * 4 + 0];
            const float k1  = rbff[8 + g * 4 + 1];
            const float nh0 = rbff[8 + g * 4 + 2];
            const float lin = rbff[8 + g * 4 + 3];
            float4 v0 = *(const float4*)(xr + g * 8);
            float4 v1 = *(const float4*)(xr + g * 8 + 4);
            float xv[8] = {v0.x, v0.y, v0.z, v0.w, v1.x, v1.y, v1.z, v1.w};
            float act[8];
#pragma unroll
            for (int f = 0; f < 8; ++f) {
                float v = xv[f];
                float dv = v - c0;
                float E0 = __expf(nh0 * dv * dv);
                float T  = __expf(k1 * dv);
                float poly = rbff[64 + g * 8 + 7];
#pragma unroll
                for (int k = 6; k >= 0; --k) poly = poly * T + rbff[64 + g * 8 + k];
                act[f] = lin * v + E0 * poly;
            }
#pragma unroll
            for (int f = 0; f < 8; ++f) {
                const float* m = Mt + (g * 8 + f) * 20;   // uniform base
                float av = act[f];
#pragma unroll
                for (int j = 0; j < 20; ++j) zp[j] += av * m[j];
            }
        }
    } else {
#pragma unroll 1
        for (int g = 0; g < 8; ++g) {
            const float lin = linw[g];
            float4 v0 = *(const float4*)(xr + g * 8);
            float4 v1 = *(const float4*)(xr + g * 8 + 4);
            float xv[8] = {v0.x, v0.y, v0.z, v0.w, v1.x, v1.y, v1.z, v1.w};
            float act[8];
#pragma unroll
            for (int f = 0; f < 8; ++f) act[f] = lin * xv[f];
#pragma unroll 1
            for (int k = 0; k < 8; ++k) {
                const float ck = rbfx[g * 8 + k];
                const float wk = rbfx[64 + g * 8 + k];
                const float nk = rbfx[128 + g * 8 + k];
#pragma unroll
                for (int f = 0; f < 8; ++f) {
                    float d = xv[f] - ck;
                    act[f] += wk * __expf(d * d * nk);
                }
            }
#pragma unroll
            for (int f = 0; f < 8; ++f) {
                const float* m = Mt + (g * 8 + f) * 20;
                float av = act[f];
#pragma unroll
                for (int j = 0; j < 20; ++j) zp[j] += av * m[j];
            }
        }
    }

#pragma unroll
    for (int j = 0; j < 20; ++j) zout[(size_t)j * B_N + row] = zp[j];

    float s_[20], q_[20];
#pragma unroll
    for (int j = 0; j < 20; ++j) { s_[j] = zp[j]; q_[j] = zp[j] * zp[j]; }
#pragma unroll
    for (int off = 32; off >= 1; off >>= 1) {
#pragma unroll
        for (int j = 0; j < 20; ++j) {
            s_[j] += __shfl_down(s_[j], off, 64);
            q_[j] += __shfl_down(q_[j], off, 64);
        }
    }
    const int wave = t >> 6, lane = t & 63;
    if (lane == 0) {
#pragma unroll
        for (int j = 0; j < 20; ++j) { sRed[wave][j] = s_[j]; sRed[wave][20 + j] = q_[j]; }
    }
    __syncthreads();
    if (t < 40) {
        float v = sRed[0][t] + sRed[1][t] + sRed[2][t] + sRed[3][t];
        atomicAdd(&stat2[(blockIdx.x & 63) * 40 + t], v);
    }
}

// ---------------- pass 3: BN2 + GELU + fuzzy + head, scalar params ----------------
__global__ __launch_bounds__(256) void k_out(
    const float* __restrict__ zin, const float* __restrict__ stat2,
    const float* __restrict__ g2, const float* __restrict__ b2,
    const float* __restrict__ nh, const float* __restrict__ fzc,
    const float* __restrict__ hW, const float* __restrict__ hb,
    float* __restrict__ out)
{
    __shared__ float sT[40], sSc[20], sSh[20];
    const int t = threadIdx.x;
    if (t < 40) {
        float s = 0.0f;
        for (int st = 0; st < 64; ++st) s += stat2[st * 40 + t];
        sT[t] = s;
    }
    __syncthreads();
    if (t < 20) {
        float mu = sT[t] * (1.0f / B_N);
        float var = fmaxf(sT[20 + t] * (1.0f / B_N) - mu * mu, 0.0f);
        float sc = g2[t] * rsqrtf(var + 1e-5f);
        sSc[t] = sc;
        sSh[t] = b2[t] - mu * sc;
    }
    __syncthreads();

    const int row = blockIdx.x * 256 + t;
    float z[20];
#pragma unroll
    for (int j = 0; j < 20; ++j) {
        float v = zin[(size_t)j * B_N + row];
        z[j] = gelu_exact(sSc[j] * v + sSh[j]);
    }
    float acc = hb[0];
#pragma unroll 1
    for (int r = 0; r < 10; ++r) {
        float u = 0.0f, l = 0.0f;
#pragma unroll
        for (int j = 0; j < 20; ++j) {
            float cx = fzc[r * 20 + j];
            float pu = nh[r * 20 + j];
            float pl = nh[200 + r * 20 + j];
            float d = z[j] - cx;
            float dd = d * d;
            u += __expf(dd * pu);
            l += __expf(dd * pl);
        }
        acc += hW[r] * 0.025f * (u + l);
    }
    out[row] = acc;
}

// ---------------- launcher ----------------
extern "C" void kernel_launch(void* const* d_in, const int* in_sizes, int n_in,
                              void* d_out, int out_size, void* d_ws, size_t ws_size,
                              hipStream_t stream) {
    const float* x    = (const float*)d_in[0];
    const float* cen  = (const float*)d_in[1];
    const float* lw   = (const float*)d_in[2];
    const float* rw   = (const float*)d_in[3];
    const float* linw = (const float*)d_in[4];
    const float* Wp   = (const float*)d_in[5];
    const float* pb   = (const float*)d_in[6];
    const float* g1   = (const float*)d_in[7];
    const float* b1   = (const float*)d_in[8];
    const float* fpW  = (const float*)d_in[9];
    const float* fpb  = (const float*)d_in[10];
    const float* g2   = (const float*)d_in[11];
    const float* b2   = (const float*)d_in[12];
    const float* fzc  = (const float*)d_in[13];
    const float* lsu  = (const float*)d_in[14];
    const float* lsl  = (const float*)d_in[15];
    const float* hW   = (const float*)d_in[16];
    const float* hb   = (const float*)d_in[17];

    float* ws    = (float*)d_ws;
    float* stat1 = ws + WS_STAT1;
    float* Mt    = ws + WS_MT;
    float* Cc    = ws + WS_C;
    float* stat2 = ws + WS_STAT2;
    float* nh    = ws + WS_NH;
    float* rbff  = ws + WS_RBFF;
    float* rbfx  = ws + WS_RBFX;
    float* zbuf  = ws + WS_Z;
    float* outp  = (float*)d_out;

    hipMemsetAsync(stat1, 0, (size_t)ST1_SZ * sizeof(float), stream);
    k_act_moments<<<1024, 256, 0, stream>>>(x, cen, lw, rw, linw, stat1);
    k_build<<<1, 256, 0, stream>>>(stat1, fpW, fpb, g1, b1, Wp, pb, lsu, lsl,
                                   cen, lw, rw, linw,
                                   Mt, Cc, nh, stat2, rbff, rbfx);
    k_z<<<512, 256, 0, stream>>>(x, Mt, Cc, rbff, rbfx, linw, zbuf, stat2);
    k_out<<<512, 256, 0, stream>>>(zbuf, stat2, g2, b2, nh, fzc, hW, hb, outp);
}

// Round 11
// 166.239 us; speedup vs baseline: 1.0686x; 1.0686x over previous
//
#include <hip/hip_runtime.h>
#include <hip/hip_fp16.h>
#include <math.h>

#define B_N 131072

// ---------------- ws layout (float offsets) ----------------
#define WS_STAT1 0
#define ST1_SZ   (64 * 352)          // 22528
#define WS_MT    22528               // Mt[64][20]
#define WS_C     23808               // C[20]
#define WS_STAT2 23840               // 64 stripes x 40 -> 26400
#define WS_NH    26400               // nhu[200], nhl[200] -> 26800
#define WS_ACTH  26816               // act fp16 [B][64]  (B*32 floats of storage)
#define WS_Z     (26816 + (size_t)B_N * 32)   // z col-major [20][B]
#define WS_END   (WS_Z + (size_t)B_N * 20)

struct alignas(16) H8 { __half2 a, b, c, d; };

__device__ __forceinline__ float gelu_exact(float v) {
    return 0.5f * v * (1.0f + erff(v * 0.70710678118654752440f));
}

// ---------------- pass 1: RBF -> act (fp16 store) + act moments ----------------
// Fast path: uniform centre grid + shared width per group -> 2 exps + Horner
// instead of 8 exps per feature. Runtime-verified, wave-uniform branch.
__global__ __launch_bounds__(256) void k_act_moments(
    const float* __restrict__ x, const float* __restrict__ cen,
    const float* __restrict__ lw, const float* __restrict__ rw,
    const float* __restrict__ linw, __half* __restrict__ act_h,
    float* __restrict__ stat1, int store)
{
    __shared__ float sAcc[4][8][44];
    const int t = threadIdx.x;
    const int g = t & 7;
    const int rl = t >> 3;

    float c_[8], nh_[8], w_[8];
#pragma unroll
    for (int k = 0; k < 8; ++k) {
        c_[k] = cen[g * 8 + k];
        float s = expf(lw[g * 8 + k]) + 1e-6f;
        nh_[k] = -0.5f / (s * s);
        w_[k] = rw[g * 8 + k];
    }
    const float lin = linw[g];
    const float c0 = c_[0], nh0 = nh_[0];
    const float delta = c_[1] - c_[0];

    // uniformity check (per lane, then wave-uniform via __all)
    bool uni = true;
#pragma unroll
    for (int k = 0; k < 8; ++k) {
        float ck = c0 + (float)k * delta;
        uni = uni && (fabsf(c_[k] - ck) <= 1e-5f * (1.0f + fabsf(ck)));
        uni = uni && (fabsf(nh_[k] - nh0) <= 1e-6f * fabsf(nh0));
    }
    const bool fast = (bool)__all((int)uni);

    float W_[8];
    float k1 = 0.0f;
    if (fast) {
        k1 = -2.0f * delta * nh0;
#pragma unroll
        for (int k = 0; k < 8; ++k) {
            float kd = (float)k * delta;
            W_[k] = w_[k] * __expf(nh0 * kd * kd);
        }
    }

    float sumA[8], P[36];
#pragma unroll
    for (int f = 0; f < 8; ++f) sumA[f] = 0.0f;
#pragma unroll
    for (int i = 0; i < 36; ++i) P[i] = 0.0f;

    if (fast) {
#pragma unroll 1
        for (int row = blockIdx.x * 32 + rl; row < B_N; row += gridDim.x * 32) {
            const float* xr = x + (size_t)row * 64 + g * 8;
            float4 v0 = *(const float4*)(xr);
            float4 v1 = *(const float4*)(xr + 4);
            float xv[8] = {v0.x, v0.y, v0.z, v0.w, v1.x, v1.y, v1.z, v1.w};
            float act[8];
#pragma unroll
            for (int f = 0; f < 8; ++f) {
                float v = xv[f];
                float dv = v - c0;
                float E0 = __expf(nh0 * dv * dv);
                float T  = __expf(k1 * dv);
                float poly = W_[7];
#pragma unroll
                for (int k = 6; k >= 0; --k) poly = poly * T + W_[k];
                act[f] = lin * v + E0 * poly;
            }
            if (store) {
                H8 h;
                h.a = __floats2half2_rn(act[0], act[1]);
                h.b = __floats2half2_rn(act[2], act[3]);
                h.c = __floats2half2_rn(act[4], act[5]);
                h.d = __floats2half2_rn(act[6], act[7]);
                *(H8*)(act_h + (size_t)row * 64 + g * 8) = h;
            }
            int idx = 0;
#pragma unroll
            for (int f = 0; f < 8; ++f) {
                sumA[f] += act[f];
#pragma unroll
                for (int f2 = 0; f2 <= f; ++f2) { P[idx] += act[f] * act[f2]; ++idx; }
            }
        }
    } else {
#pragma unroll 1
        for (int row = blockIdx.x * 32 + rl; row < B_N; row += gridDim.x * 32) {
            const float* xr = x + (size_t)row * 64 + g * 8;
            float4 v0 = *(const float4*)(xr);
            float4 v1 = *(const float4*)(xr + 4);
            float xv[8] = {v0.x, v0.y, v0.z, v0.w, v1.x, v1.y, v1.z, v1.w};
            float act[8];
#pragma unroll
            for (int f = 0; f < 8; ++f) {
                float v = xv[f];
                float a = lin * v;
#pragma unroll
                for (int k = 0; k < 8; ++k) {
                    float d = v - c_[k];
                    a += w_[k] * __expf(d * d * nh_[k]);
                }
                act[f] = a;
            }
            if (store) {
                H8 h;
                h.a = __floats2half2_rn(act[0], act[1]);
                h.b = __floats2half2_rn(act[2], act[3]);
                h.c = __floats2half2_rn(act[4], act[5]);
                h.d = __floats2half2_rn(act[6], act[7]);
                *(H8*)(act_h + (size_t)row * 64 + g * 8) = h;
            }
            int idx = 0;
#pragma unroll
            for (int f = 0; f < 8; ++f) {
                sumA[f] += act[f];
#pragma unroll
                for (int f2 = 0; f2 <= f; ++f2) { P[idx] += act[f] * act[f2]; ++idx; }
            }
        }
    }

#pragma unroll
    for (int off = 32; off >= 8; off >>= 1) {
#pragma unroll
        for (int f = 0; f < 8; ++f) sumA[f] += __shfl_down(sumA[f], off, 64);
#pragma unroll
        for (int i = 0; i < 36; ++i) P[i] += __shfl_down(P[i], off, 64);
    }
    const int wave = t >> 6, lane = t & 63;
    if (lane < 8) {   // lane == g
        float* dst = &sAcc[wave][lane][0];
#pragma unroll
        for (int f = 0; f < 8; ++f) dst[f] = sumA[f];
#pragma unroll
        for (int i = 0; i < 36; ++i) dst[8 + i] = P[i];
    }
    __syncthreads();
    for (int i = t; i < 352; i += 256) {
        int gg = i / 44, v = i % 44;
        float s = sAcc[0][gg][v] + sAcc[1][gg][v] + sAcc[2][gg][v] + sAcc[3][gg][v];
        atomicAdd(&stat1[(blockIdx.x & 63) * 352 + i], s);
    }
}

// ---------------- build: BN1 fold -> Mt/C, fuzzy tables, zero stat2 ----------------
__global__ __launch_bounds__(256) void k_build(
    const float* __restrict__ stat1, const float* __restrict__ fpW,
    const float* __restrict__ fpb, const float* __restrict__ g1,
    const float* __restrict__ b1, const float* __restrict__ Wp,
    const float* __restrict__ pb, const float* __restrict__ lsu,
    const float* __restrict__ lsl,
    float* __restrict__ Mt, float* __restrict__ Cc, float* __restrict__ nh,
    float* __restrict__ stat2)
{
    __shared__ float Am[8][8];
    __shared__ float Sg[8][36];
    __shared__ float a_[128], bb_[128];
    const int t = threadIdx.x;
    for (int i = t; i < 352; i += 256) {
        float s = 0.0f;
        for (int st = 0; st < 64; ++st) s += stat1[st * 352 + i];
        float m = s * (1.0f / B_N);
        int g = i / 44, v = i % 44;
        if (v < 8) Am[g][v] = m; else Sg[g][v - 8] = m;
    }
    __syncthreads();
    if (t < 128) {
        const int g = t >> 4;
        float wv[8];
#pragma unroll
        for (int f = 0; f < 8; ++f) wv[f] = Wp[t * 8 + f];
        float dot = 0.0f;
#pragma unroll
        for (int f = 0; f < 8; ++f) dot += wv[f] * Am[g][f];
        const float pbv = pb[t];
        const float mu = pbv + dot;
        float e2 = pbv * pbv + 2.0f * pbv * dot;
        int idx = 0;
#pragma unroll
        for (int f = 0; f < 8; ++f)
#pragma unroll
            for (int f2 = 0; f2 <= f; ++f2) {
                float c2 = (f2 == f) ? 1.0f : 2.0f;
                e2 += c2 * wv[f] * wv[f2] * Sg[g][idx]; ++idx;
            }
        const float var = fmaxf(e2 - mu * mu, 0.0f);
        const float a = g1[t] * rsqrtf(var + 1e-5f);
        a_[t] = a;
        bb_[t] = b1[t] - mu * a;
    }
    __syncthreads();
    for (int i = t; i < 1280; i += 256) {
        int gf = i / 20, j = i % 20;
        int g = gf >> 3, f = gf & 7;
        float m = 0.0f;
        for (int o = 0; o < 16; ++o) {
            int c = g * 16 + o;
            m += fpW[j * 128 + c] * a_[c] * Wp[c * 8 + f];
        }
        Mt[i] = m;
    }
    if (t < 20) {
        float cj = fpb[t];
        for (int c = 0; c < 128; ++c)
            cj += fpW[t * 128 + c] * (a_[c] * pb[c] + bb_[c]);
        Cc[t] = cj;
    }
    for (int i = t; i < 200; i += 256) {
        float su = expf(lsu[i]) + 1e-6f;
        float sl = fminf(expf(lsl[i]) + 1e-6f, 0.9f * su);
        nh[i] = -0.5f / (su * su);
        nh[200 + i] = -0.5f / (sl * sl);
    }
    for (int i = t; i < 2560; i += 256) stat2[i] = 0.0f;
}

// ---------------- pass 2: z = act_h · Mt + C, scalar-Mt, 1 row/thread ----------------
__global__ __launch_bounds__(256) void k_z(
    const __half* __restrict__ act_h, const float* __restrict__ Mt,
    const float* __restrict__ Cc, float* __restrict__ zout,
    float* __restrict__ stat2)
{
    __shared__ float sRed[4][40];
    const int t = threadIdx.x;
    const int row = blockIdx.x * 256 + t;

    float zp[20];
#pragma unroll
    for (int j = 0; j < 20; ++j) zp[j] = Cc[j];   // uniform -> s_load

#pragma unroll 1
    for (int g = 0; g < 8; ++g) {
        const H8 h = *(const H8*)(act_h + (size_t)row * 64 + g * 8);
        float2 f0 = __half22float2(h.a), f1 = __half22float2(h.b);
        float2 f2 = __half22float2(h.c), f3 = __half22float2(h.d);
        float a[8] = {f0.x, f0.y, f1.x, f1.y, f2.x, f2.y, f3.x, f3.y};
#pragma unroll
        for (int f = 0; f < 8; ++f) {
            const float* m = Mt + (g * 8 + f) * 20;   // uniform base
            float av = a[f];
#pragma unroll
            for (int j = 0; j < 20; ++j) zp[j] += av * m[j];   // v_fmac v,s,v
        }
    }

#pragma unroll
    for (int j = 0; j < 20; ++j) zout[(size_t)j * B_N + row] = zp[j];

    float s_[20], q_[20];
#pragma unroll
    for (int j = 0; j < 20; ++j) { s_[j] = zp[j]; q_[j] = zp[j] * zp[j]; }
#pragma unroll
    for (int off = 32; off >= 1; off >>= 1) {
#pragma unroll
        for (int j = 0; j < 20; ++j) {
            s_[j] += __shfl_down(s_[j], off, 64);
            q_[j] += __shfl_down(q_[j], off, 64);
        }
    }
    const int wave = t >> 6, lane = t & 63;
    if (lane == 0) {
#pragma unroll
        for (int j = 0; j < 20; ++j) { sRed[wave][j] = s_[j]; sRed[wave][20 + j] = q_[j]; }
    }
    __syncthreads();
    if (t < 40) {
        float v = sRed[0][t] + sRed[1][t] + sRed[2][t] + sRed[3][t];
        atomicAdd(&stat2[(blockIdx.x & 63) * 40 + t], v);
    }
}

// ---------------- fallback pass 2 (ws too small): recompute RBF ----------------
__global__ __launch_bounds__(256) void k_zpre_stats(
    const float* __restrict__ x, const float* __restrict__ cen,
    const float* __restrict__ lw, const float* __restrict__ rw,
    const float* __restrict__ linw, const float* __restrict__ Mt,
    const float* __restrict__ Cc, float* __restrict__ zout,
    float* __restrict__ stat2)
{
    __shared__ __align__(16) float4 sRbf[64];
    __shared__ float sLin[8], sC[20];
    __shared__ __align__(16) float sMt[1280];
    __shared__ float sRed[4][40];
    const int t = threadIdx.x;
    if (t < 64) {
        float s = expf(lw[t]) + 1e-6f;
        sRbf[t] = make_float4(cen[t], rw[t], -0.5f / (s * s), 0.0f);
    }
    if (t < 8)  sLin[t] = linw[t];
    if (t < 20) sC[t] = Cc[t];
    for (int i = t; i < 1280; i += 256) sMt[i] = Mt[i];
    __syncthreads();
    const int row = blockIdx.x * 256 + t;
    const float* xr = x + (size_t)row * 64;
    float zp[20];
#pragma unroll
    for (int j = 0; j < 20; ++j) zp[j] = sC[j];
#pragma unroll 1
    for (int g = 0; g < 8; ++g) {
        float4 v0 = *(const float4*)(xr + g * 8);
        float4 v1 = *(const float4*)(xr + g * 8 + 4);
        float xv[8] = {v0.x, v0.y, v0.z, v0.w, v1.x, v1.y, v1.z, v1.w};
        float act[8];
        float lin = sLin[g];
#pragma unroll
        for (int f = 0; f < 8; ++f) act[f] = lin * xv[f];
#pragma unroll 1
        for (int k = 0; k < 8; ++k) {
            float4 p = sRbf[g * 8 + k];
#pragma unroll
            for (int f = 0; f < 8; ++f) {
                float d = xv[f] - p.x;
                act[f] += p.y * __expf(d * d * p.z);
            }
        }
#pragma unroll 1
        for (int f = 0; f < 8; ++f) {
            float av = act[f];
            const float4* m4 = (const float4*)(sMt + (g * 8 + f) * 20);
            float4 ma = m4[0], mb = m4[1], mc = m4[2], md = m4[3], me = m4[4];
            zp[0] += av * ma.x; zp[1] += av * ma.y; zp[2] += av * ma.z; zp[3] += av * ma.w;
            zp[4] += av * mb.x; zp[5] += av * mb.y; zp[6] += av * mb.z; zp[7] += av * mb.w;
            zp[8] += av * mc.x; zp[9] += av * mc.y; zp[10] += av * mc.z; zp[11] += av * mc.w;
            zp[12] += av * md.x; zp[13] += av * md.y; zp[14] += av * md.z; zp[15] += av * md.w;
            zp[16] += av * me.x; zp[17] += av * me.y; zp[18] += av * me.z; zp[19] += av * me.w;
        }
    }
#pragma unroll
    for (int j = 0; j < 20; ++j) zout[(size_t)j * B_N + row] = zp[j];
    float s_[20], q_[20];
#pragma unroll
    for (int j = 0; j < 20; ++j) { s_[j] = zp[j]; q_[j] = zp[j] * zp[j]; }
#pragma unroll
    for (int off = 32; off >= 1; off >>= 1) {
#pragma unroll
        for (int j = 0; j < 20; ++j) {
            s_[j] += __shfl_down(s_[j], off, 64);
            q_[j] += __shfl_down(q_[j], off, 64);
        }
    }
    const int wave = t >> 6, lane = t & 63;
    if (lane == 0) {
#pragma unroll
        for (int j = 0; j < 20; ++j) { sRed[wave][j] = s_[j]; sRed[wave][20 + j] = q_[j]; }
    }
    __syncthreads();
    if (t < 40) {
        float v = sRed[0][t] + sRed[1][t] + sRed[2][t] + sRed[3][t];
        atomicAdd(&stat2[(blockIdx.x & 63) * 40 + t], v);
    }
}

// ---------------- pass 3: BN2 + GELU + fuzzy + head, scalar params ----------------
__global__ __launch_bounds__(256) void k_out(
    const float* __restrict__ zin, const float* __restrict__ stat2,
    const float* __restrict__ g2, const float* __restrict__ b2,
    const float* __restrict__ nh, const float* __restrict__ fzc,
    const float* __restrict__ hW, const float* __restrict__ hb,
    float* __restrict__ out)
{
    __shared__ float sT[40], sSc[20], sSh[20];
    const int t = threadIdx.x;
    if (t < 40) {
        float s = 0.0f;
        for (int st = 0; st < 64; ++st) s += stat2[st * 40 + t];
        sT[t] = s;
    }
    __syncthreads();
    if (t < 20) {
        float mu = sT[t] * (1.0f / B_N);
        float var = fmaxf(sT[20 + t] * (1.0f / B_N) - mu * mu, 0.0f);
        float sc = g2[t] * rsqrtf(var + 1e-5f);
        sSc[t] = sc;
        sSh[t] = b2[t] - mu * sc;
    }
    __syncthreads();

    const int row = blockIdx.x * 256 + t;
    float z[20];
#pragma unroll
    for (int j = 0; j < 20; ++j) {
        float v = zin[(size_t)j * B_N + row];
        z[j] = gelu_exact(sSc[j] * v + sSh[j]);
    }
    float acc = hb[0];
#pragma unroll 1
    for (int r = 0; r < 10; ++r) {
        float u = 0.0f, l = 0.0f;
#pragma unroll
        for (int j = 0; j < 20; ++j) {
            float cx = fzc[r * 20 + j];
            float pu = nh[r * 20 + j];
            float pl = nh[200 + r * 20 + j];
            float d = z[j] - cx;
            float dd = d * d;
            u += __expf(dd * pu);
            l += __expf(dd * pl);
        }
        acc += hW[r] * 0.025f * (u + l);
    }
    out[row] = acc;
}

// ---------------- launcher ----------------
extern "C" void kernel_launch(void* const* d_in, const int* in_sizes, int n_in,
                              void* d_out, int out_size, void* d_ws, size_t ws_size,
                              hipStream_t stream) {
    const float* x    = (const float*)d_in[0];
    const float* cen  = (const float*)d_in[1];
    const float* lw   = (const float*)d_in[2];
    const float* rw   = (const float*)d_in[3];
    const float* linw = (const float*)d_in[4];
    const float* Wp   = (const float*)d_in[5];
    const float* pb   = (const float*)d_in[6];
    const float* g1   = (const float*)d_in[7];
    const float* b1   = (const float*)d_in[8];
    const float* fpW  = (const float*)d_in[9];
    const float* fpb  = (const float*)d_in[10];
    const float* g2   = (const float*)d_in[11];
    const float* b2   = (const float*)d_in[12];
    const float* fzc  = (const float*)d_in[13];
    const float* lsu  = (const float*)d_in[14];
    const float* lsl  = (const float*)d_in[15];
    const float* hW   = (const float*)d_in[16];
    const float* hb   = (const float*)d_in[17];

    float* ws    = (float*)d_ws;
    float* stat1 = ws + WS_STAT1;
    float* Mt    = ws + WS_MT;
    float* Cc    = ws + WS_C;
    float* stat2 = ws + WS_STAT2;
    float* nh    = ws + WS_NH;
    __half* acth = (__half*)(ws + WS_ACTH);
    float* zbuf  = ws + WS_Z;
    float* outp  = (float*)d_out;

    const size_t needFull = WS_END * sizeof(float);
    const int mode = (ws_size >= needFull) ? 2 : 1;
    if (mode == 1) zbuf = ws + WS_ACTH;

    hipMemsetAsync(stat1, 0, (size_t)ST1_SZ * sizeof(float), stream);
    k_act_moments<<<1024, 256, 0, stream>>>(x, cen, lw, rw, linw, acth, stat1,
                                            mode == 2 ? 1 : 0);
    k_build<<<1, 256, 0, stream>>>(stat1, fpW, fpb, g1, b1, Wp, pb, lsu, lsl,
                                   Mt, Cc, nh, stat2);
    if (mode == 2) {
        k_z<<<512, 256, 0, stream>>>(acth, Mt, Cc, zbuf, stat2);
    } else {
        k_zpre_stats<<<512, 256, 0, stream>>>(x, cen, lw, rw, linw, Mt, Cc,
                                              zbuf, stat2);
    }
    k_out<<<512, 256, 0, stream>>>(zbuf, stat2, g2, b2, nh, fzc, hW, hb, outp);
}